// Round 12
// baseline (389.291 us; speedup 1.0000x reference)
//
#include <hip/hip_runtime.h>
#include <stdint.h>

#define Tdim 128
#define Zdim 100
#define Sdim 6
#define Hdim 64
#define ZB   3200           // Z*B
#define F1   512
#define F2   128

typedef _Float16 f16x8 __attribute__((ext_vector_type(8)));
typedef _Float16 f16x4 __attribute__((ext_vector_type(4)));
typedef float f32x4 __attribute__((ext_vector_type(4)));

__device__ __forceinline__ float sigmoidf_fast(float x) {
  return 1.f / (1.f + __expf(-x));
}
__device__ __forceinline__ float tanhf_fast(float x) {
  return 1.f - 2.f / (__expf(2.f * x) + 1.f);
}

// ---------------------------------------------------------------- prep
// Wf[192][96] fp16: [W_hh | W_ih | 0] per gate (K=96 fused), for the GRU.
// w1p frag-linear: [kt][ntl][kfrag][lane][8].  32768 f16.
// w2p frag-linear: [kt][nt][lane][8].          65536 f16.
__global__ __launch_bounds__(256) void prep_kernel(
    const float* __restrict__ W_ih, const float* __restrict__ W_hh,
    const float* __restrict__ w1, const float* __restrict__ w2,
    _Float16* __restrict__ Wf, _Float16* __restrict__ w1p,
    _Float16* __restrict__ w2p) {
  int i = blockIdx.x * 256 + threadIdx.x;     // grid covers 116736
  if (i < 192 * 96) {
    int g = i / 96, k = i - g * 96;
    float v = (k < 64) ? W_hh[g * 64 + k] : ((k < 70) ? W_ih[g * 6 + (k - 64)] : 0.f);
    Wf[i] = (_Float16)v;
  }
  int j = i - 192 * 96;
  if (j >= 0 && j < 32768) {
    int kt = j >> 11, ntl = (j >> 10) & 1, kf = (j >> 9) & 1;
    int lane = (j >> 3) & 63, e = j & 7;
    int q = lane >> 4, c = lane & 15;
    int row = kt * 32 + ntl * 16 + c;
    int h = kf * 32 + q * 8 + e;
    w1p[j] = (_Float16)w1[row * 64 + h];
  }
  int l = j - 32768;
  if (l >= 0 && l < 65536) {
    int kt = l >> 12, nt = (l >> 9) & 7;
    int lane = (l >> 3) & 63, e = l & 7;
    int q = lane >> 4, c = lane & 15;
    int row = nt * 16 + c;
    int k = kt * 32 + q * 8 + e;
    w2p[l] = (_Float16)w2[row * 512 + k];
  }
}

// ---------------------------------------------------------------- fused GRU+MLP
// Block = 4 waves, 16 rows; 200 blocks. GRU recurrence as R11 (wave w owns
// gate-dims [16w,16w+16) of r,z,n; h exchanged via double-buffered 16-step
// LDS hist; per-step barrier drains lgkm only). The MLP for chunk c-1 runs
// DURING chunk c on the same waves, filling the idle MFMA pipe: per step,
// 2 k-chunks x 2 row-groups = 48 MFMA, weights streamed frag-linear from L2
// (issued at step start, consumed after gate math -> cheap vmcnt drain).
// sx never exists: MLP reads h straight from hist; out written per pair.
// launch_bounds(256,1): 1 wave/SIMD by design -> up to 512 VGPRs, no spill.
__global__ __launch_bounds__(256, 1) void fused_kernel(
    const float* __restrict__ x, const _Float16* __restrict__ Wf,
    const float* __restrict__ b_ih, const float* __restrict__ b_hh,
    const _Float16* __restrict__ w1p, const _Float16* __restrict__ w2p,
    const float* __restrict__ b1, const float* __restrict__ b2,
    const float* __restrict__ w3, const float* __restrict__ b3,
    float* __restrict__ out) {
  __shared__ __align__(16) _Float16 hist[2][16][16][72];  // 72 KB (2 x 16-step)
  __shared__ __align__(16) _Float16 xs[Tdim][16][8];      // 32 KB
  __shared__ __align__(16) _Float16 rep[4][2][512];       // 8 KB
  const int tid = threadIdx.x;
  const int lane = tid & 63;
  const int w = tid >> 6;                     // wave id 0..3
  const int c = lane & 15;                    // MFMA col = row index
  const int q = lane >> 4;                    // quad

  // ---- preload x for this block's 16 rows, pre-converted to fp16
  for (int i = 0; i < 8; i++) {
    int idx = i * 256 + tid;                  // 0..2047 = (t, row)
    int t = idx >> 4, row = idx & 15;
    int nr = blockIdx.x * 16 + row;           // n = z*32 + b
    const float* p = x + (size_t)(nr & 31) * (Tdim * Zdim * Sdim)
                       + (size_t)t * (Zdim * Sdim) + (size_t)(nr >> 5) * Sdim;
    f16x8 v;
    v[0] = (_Float16)p[0]; v[1] = (_Float16)p[1]; v[2] = (_Float16)p[2];
    v[3] = (_Float16)p[3]; v[4] = (_Float16)p[4]; v[5] = (_Float16)p[5];
    v[6] = (_Float16)0.f;  v[7] = (_Float16)0.f;
    *(f16x8*)&xs[t][row][0] = v;
  }

  const int gr0 = w * 16;                     // r-gate tile base
  const int gz0 = 64 + w * 16;                // z-gate tile base
  const int gn0 = 128 + w * 16;               // n-gate tile base

  // GRU A-frags: A[m=c][k=q*8+j] per 16-gate tile, K=96 fused [h|x|0]
  f16x8 Ar[3], Az[3], Anh[2], Ani;
#pragma unroll
  for (int kf = 0; kf < 3; kf++) {
    Ar[kf] = *(const f16x8*)(Wf + (size_t)(gr0 + c) * 96 + kf * 32 + q * 8);
    Az[kf] = *(const f16x8*)(Wf + (size_t)(gz0 + c) * 96 + kf * 32 + q * 8);
  }
  Anh[0] = *(const f16x8*)(Wf + (size_t)(gn0 + c) * 96 + q * 8);
  Anh[1] = *(const f16x8*)(Wf + (size_t)(gn0 + c) * 96 + 32 + q * 8);
  Ani    = *(const f16x8*)(Wf + (size_t)(gn0 + c) * 96 + 64 + q * 8);

  // biases in D-layout (gate-local m = q*4 + r)
  f32x4 Cr, Cz, Cnh, Cni;
  {
    f32x4 bir = *(const f32x4*)(b_ih + gr0 + q * 4);
    f32x4 bhr = *(const f32x4*)(b_hh + gr0 + q * 4);
    f32x4 biz = *(const f32x4*)(b_ih + gz0 + q * 4);
    f32x4 bhz = *(const f32x4*)(b_hh + gz0 + q * 4);
#pragma unroll
    for (int r = 0; r < 4; r++) { Cr[r] = bir[r] + bhr[r]; Cz[r] = biz[r] + bhz[r]; }
    Cnh = *(const f32x4*)(b_hh + gn0 + q * 4);
    Cni = *(const f32x4*)(b_ih + gn0 + q * 4);
  }

  const int n = blockIdx.x * 16 + c;          // batch row of lane col c
  const float b3v = b3[0];

  __syncthreads();                            // xs ready

  f16x8 Bh0 = {0, 0, 0, 0, 0, 0, 0, 0};
  f16x8 Bh1 = {0, 0, 0, 0, 0, 0, 0, 0};
  f32x4 hprev = {0.f, 0.f, 0.f, 0.f};
  const f32x4 zero4 = {0.f, 0.f, 0.f, 0.f};

  // ---- pipeline seeds for t=0: x-projection MFMAs
  f32x4 Dr_s, Dz_s, Dni_s;
  {
    f16x8 xv8 = *(const f16x8*)&xs[0][c][0];
    f16x8 Bx;
#pragma unroll
    for (int j = 0; j < 8; j++) Bx[j] = (q == 0) ? xv8[j] : (_Float16)0.f;
    Dni_s = __builtin_amdgcn_mfma_f32_16x16x32_f16(Ani, Bx, Cni, 0, 0, 0);
    Dr_s  = __builtin_amdgcn_mfma_f32_16x16x32_f16(Ar[2], Bx, Cr, 0, 0, 0);
    Dz_s  = __builtin_amdgcn_mfma_f32_16x16x32_f16(Az[2], Bx, Cz, 0, 0, 0);
  }

#pragma unroll 1
  for (int tch = 0; tch < 8; tch++) {
    const int buf = tch & 1;
#pragma unroll 1
    for (int p = 0; p < 2; p++) {
      const bool mlp = (tch > 0);
      // MLP pair state: 2 groups = prev-chunk timesteps w*4+p*2+{0,1}
      f16x8 Bs[2][2];
      f32x4 acc2[2][8];
      if (mlp) {
#pragma unroll
        for (int gi = 0; gi < 2; gi++) {
          const int tcg = w * 4 + p * 2 + gi;
          Bs[gi][0] = *(const f16x8*)&hist[buf ^ 1][tcg][c][q * 8];
          Bs[gi][1] = *(const f16x8*)&hist[buf ^ 1][tcg][c][32 + q * 8];
#pragma unroll
          for (int nt = 0; nt < 8; nt++) acc2[gi][nt] = zero4;
        }
      }
#pragma unroll 1
      for (int sp = 0; sp < 8; sp++) {
        const int tc = p * 8 + sp;
        const int t = tch * 16 + tc;
        // ---- MLP weight loads for this step's 2 k-chunks (issue EARLY)
        f16x8 W1v[2][4], W2v[2][8];
        f32x4 bb1[2][2];
        if (mlp) {
#pragma unroll
          for (int kk = 0; kk < 2; kk++) {
            const int kt = sp * 2 + kk;
            const _Float16* w1g = w1p + (size_t)kt * 2048 + lane * 8;
            const _Float16* w2g = w2p + (size_t)kt * 4096 + lane * 8;
#pragma unroll
            for (int f = 0; f < 4; f++) W1v[kk][f] = *(const f16x8*)(w1g + f * 512);
#pragma unroll
            for (int nt = 0; nt < 8; nt++) W2v[kk][nt] = *(const f16x8*)(w2g + nt * 512);
            bb1[kk][0] = *(const f32x4*)(b1 + kt * 32 + q * 4);
            bb1[kk][1] = *(const f32x4*)(b1 + kt * 32 + 16 + q * 4);
          }
        }
        // ---- GRU h-MFMAs: 6 independent partials, one dep level
        f32x4 Dnh0 = __builtin_amdgcn_mfma_f32_16x16x32_f16(Anh[0], Bh0, Cnh, 0, 0, 0);
        f32x4 Dr0  = __builtin_amdgcn_mfma_f32_16x16x32_f16(Ar[0], Bh0, Dr_s, 0, 0, 0);
        f32x4 Dz0  = __builtin_amdgcn_mfma_f32_16x16x32_f16(Az[0], Bh0, Dz_s, 0, 0, 0);
        f32x4 Dnh1 = __builtin_amdgcn_mfma_f32_16x16x32_f16(Anh[1], Bh1, zero4, 0, 0, 0);
        f32x4 Dr1  = __builtin_amdgcn_mfma_f32_16x16x32_f16(Ar[1], Bh1, zero4, 0, 0, 0);
        f32x4 Dz1  = __builtin_amdgcn_mfma_f32_16x16x32_f16(Az[1], Bh1, zero4, 0, 0, 0);

        f16x4 pk;
#pragma unroll
        for (int r = 0; r < 4; r++) {
          float rr = sigmoidf_fast(Dr0[r] + Dr1[r]);
          float zg = sigmoidf_fast(Dz0[r] + Dz1[r]);
          float nn = tanhf_fast(Dni_s[r] + rr * (Dnh0[r] + Dnh1[r]));
          float hnew = nn + zg * (hprev[r] - nn);
          hprev[r] = hnew;
          pk[r] = (_Float16)hnew;
        }
        *(f16x4*)&hist[buf][tc][c][w * 16 + q * 4] = pk;

        // ---- pre-barrier: x-projection for t+1 (h-independent)
        if (t + 1 < Tdim) {
          f16x8 xv8 = *(const f16x8*)&xs[t + 1][c][0];
          f16x8 Bx;
#pragma unroll
          for (int j = 0; j < 8; j++) Bx[j] = (q == 0) ? xv8[j] : (_Float16)0.f;
          Dni_s = __builtin_amdgcn_mfma_f32_16x16x32_f16(Ani, Bx, Cni, 0, 0, 0);
          Dr_s  = __builtin_amdgcn_mfma_f32_16x16x32_f16(Ar[2], Bx, Cr, 0, 0, 0);
          Dz_s  = __builtin_amdgcn_mfma_f32_16x16x32_f16(Az[2], Bx, Cz, 0, 0, 0);
        }

        // ---- MLP compute for the 2 k-chunks (fills the MFMA pipe)
        if (mlp) {
#pragma unroll
          for (int kk = 0; kk < 2; kk++) {
#pragma unroll
            for (int ntl = 0; ntl < 2; ntl++) {
              const int roff = ((2 * ntl + (q >> 1)) * 16 + c) * 8 + (q & 1) * 4;
#pragma unroll
              for (int gi = 0; gi < 2; gi++) {
                f32x4 cc = __builtin_amdgcn_mfma_f32_16x16x32_f16(W1v[kk][ntl * 2], Bs[gi][0], bb1[kk][ntl], 0, 0, 0);
                cc = __builtin_amdgcn_mfma_f32_16x16x32_f16(W1v[kk][ntl * 2 + 1], Bs[gi][1], cc, 0, 0, 0);
                f16x4 pk2;
#pragma unroll
                for (int r = 0; r < 4; r++)
                  pk2[r] = (_Float16)(cc[r] > 0.f ? cc[r] : 0.f);
                *(f16x4*)&rep[w][gi][roff] = pk2;
              }
            }
            f16x8 Ba[2];
#pragma unroll
            for (int gi = 0; gi < 2; gi++)
              Ba[gi] = *(const f16x8*)&rep[w][gi][lane * 8];
#pragma unroll
            for (int nt = 0; nt < 8; nt++)
#pragma unroll
              for (int gi = 0; gi < 2; gi++)
                acc2[gi][nt] = __builtin_amdgcn_mfma_f32_16x16x32_f16(W2v[kk][nt], Ba[gi], acc2[gi][nt], 0, 0, 0);
          }
        }
        __syncthreads();                      // lgkm drain; weight loads landed
        Bh0 = *(const f16x8*)&hist[buf][tc][c][q * 8];
        Bh1 = *(const f16x8*)&hist[buf][tc][c][32 + q * 8];
      } // sp
      // ---- layer3 for the finished pair + out store
      if (mlp) {
#pragma unroll
        for (int gi = 0; gi < 2; gi++) {
          float part = 0.f;
#pragma unroll
          for (int nt = 0; nt < 8; nt++) {
            f32x4 bb = *(const f32x4*)(b2 + nt * 16 + q * 4);
            f32x4 ww = *(const f32x4*)(w3 + nt * 16 + q * 4);
#pragma unroll
            for (int r = 0; r < 4; r++) {
              float v = acc2[gi][nt][r] + bb[r];
              v = v > 0.f ? v : 0.f;
              part = fmaf(v, ww[r], part);
            }
          }
          part += __shfl_xor(part, 16, 64);
          part += __shfl_xor(part, 32, 64);
          if (q == 0)
            out[(size_t)n * Tdim + (tch - 1) * 16 + w * 4 + p * 2 + gi] = part + b3v;
        }
      }
    } // p
  } // tch

  // ---- drain: MLP for the last chunk (hist[1]), no GRU, no barriers
#pragma unroll 1
  for (int p = 0; p < 2; p++) {
    f16x8 Bs[2][2];
    f32x4 acc2[2][8];
#pragma unroll
    for (int gi = 0; gi < 2; gi++) {
      const int tcg = w * 4 + p * 2 + gi;
      Bs[gi][0] = *(const f16x8*)&hist[1][tcg][c][q * 8];
      Bs[gi][1] = *(const f16x8*)&hist[1][tcg][c][32 + q * 8];
#pragma unroll
      for (int nt = 0; nt < 8; nt++) acc2[gi][nt] = (f32x4){0.f, 0.f, 0.f, 0.f};
    }
#pragma unroll 1
    for (int kt = 0; kt < 16; kt++) {
      const _Float16* w1g = w1p + (size_t)kt * 2048 + lane * 8;
      const _Float16* w2g = w2p + (size_t)kt * 4096 + lane * 8;
      f16x8 W1v[4], W2v[8];
#pragma unroll
      for (int f = 0; f < 4; f++) W1v[f] = *(const f16x8*)(w1g + f * 512);
#pragma unroll
      for (int nt = 0; nt < 8; nt++) W2v[nt] = *(const f16x8*)(w2g + nt * 512);
      f32x4 bb1a = *(const f32x4*)(b1 + kt * 32 + q * 4);
      f32x4 bb1b = *(const f32x4*)(b1 + kt * 32 + 16 + q * 4);
#pragma unroll
      for (int ntl = 0; ntl < 2; ntl++) {
        const int roff = ((2 * ntl + (q >> 1)) * 16 + c) * 8 + (q & 1) * 4;
#pragma unroll
        for (int gi = 0; gi < 2; gi++) {
          f32x4 cc = __builtin_amdgcn_mfma_f32_16x16x32_f16(W1v[ntl * 2], Bs[gi][0], ntl ? bb1b : bb1a, 0, 0, 0);
          cc = __builtin_amdgcn_mfma_f32_16x16x32_f16(W1v[ntl * 2 + 1], Bs[gi][1], cc, 0, 0, 0);
          f16x4 pk2;
#pragma unroll
          for (int r = 0; r < 4; r++)
            pk2[r] = (_Float16)(cc[r] > 0.f ? cc[r] : 0.f);
          *(f16x4*)&rep[w][gi][roff] = pk2;
        }
      }
      f16x8 Ba[2];
#pragma unroll
      for (int gi = 0; gi < 2; gi++)
        Ba[gi] = *(const f16x8*)&rep[w][gi][lane * 8];
#pragma unroll
      for (int nt = 0; nt < 8; nt++)
#pragma unroll
        for (int gi = 0; gi < 2; gi++)
          acc2[gi][nt] = __builtin_amdgcn_mfma_f32_16x16x32_f16(W2v[nt], Ba[gi], acc2[gi][nt], 0, 0, 0);
    }
#pragma unroll
    for (int gi = 0; gi < 2; gi++) {
      float part = 0.f;
#pragma unroll
      for (int nt = 0; nt < 8; nt++) {
        f32x4 bb = *(const f32x4*)(b2 + nt * 16 + q * 4);
        f32x4 ww = *(const f32x4*)(w3 + nt * 16 + q * 4);
#pragma unroll
        for (int r = 0; r < 4; r++) {
          float v = acc2[gi][nt][r] + bb[r];
          v = v > 0.f ? v : 0.f;
          part = fmaf(v, ww[r], part);
        }
      }
      part += __shfl_xor(part, 16, 64);
      part += __shfl_xor(part, 32, 64);
      if (q == 0)
        out[(size_t)n * Tdim + 7 * 16 + w * 4 + p * 2 + gi] = part + b3v;
    }
  }
}

// ----------------------------------------------------------------
extern "C" void kernel_launch(void* const* d_in, const int* in_sizes, int n_in,
                              void* d_out, int out_size, void* d_ws, size_t ws_size,
                              hipStream_t stream) {
  const float* x    = (const float*)d_in[0];
  const float* W_ih = (const float*)d_in[1];
  const float* W_hh = (const float*)d_in[2];
  const float* b_ih = (const float*)d_in[3];
  const float* b_hh = (const float*)d_in[4];
  const float* w1   = (const float*)d_in[5];
  const float* b1   = (const float*)d_in[6];
  const float* w2   = (const float*)d_in[7];
  const float* b2   = (const float*)d_in[8];
  const float* w3   = (const float*)d_in[9];
  const float* b3   = (const float*)d_in[10];
  float* out = (float*)d_out;

  char* ws = (char*)d_ws;
  _Float16* Wf  = (_Float16*)ws;                          // 36,864 B
  _Float16* w1p = (_Float16*)(ws + 36864);                // 65,536 B
  _Float16* w2p = (_Float16*)(ws + 36864 + 65536);        // 131,072 B

  hipLaunchKernelGGL(prep_kernel, dim3(456), dim3(256), 0, stream,
                     W_ih, W_hh, w1, w2, Wf, w1p, w2p);
  hipLaunchKernelGGL(fused_kernel, dim3(ZB / 16), dim3(256), 0, stream,
                     x, Wf, b_ih, b_hh, w1p, w2p, b1, b2, w3, b3, out);
}

// Round 13
// 356.624 us; speedup vs baseline: 1.0916x; 1.0916x over previous
//
#include <hip/hip_runtime.h>
#include <stdint.h>

#define Tdim 128
#define Zdim 100
#define Sdim 6
#define Hdim 64
#define ZB   3200           // Z*B
#define F1   512
#define F2   128

typedef _Float16 f16x8 __attribute__((ext_vector_type(8)));
typedef _Float16 f16x4 __attribute__((ext_vector_type(4)));
typedef float f32x4 __attribute__((ext_vector_type(4)));

__device__ __forceinline__ float sigmoidf_fast(float x) {
  return 1.f / (1.f + __expf(-x));
}
__device__ __forceinline__ float tanhf_fast(float x) {
  return 1.f - 2.f / (__expf(2.f * x) + 1.f);
}

// ---------------------------------------------------------------- prep
// Wf[192][96] fp16: [W_hh | W_ih | 0] per gate (K=96 fused), for the GRU.
// w1p frag-linear: [kt][ntl][kfrag][lane][8].  32768 f16.
// w2p frag-linear: [kt][nt][lane][8].          65536 f16.
__global__ __launch_bounds__(256) void prep_kernel(
    const float* __restrict__ W_ih, const float* __restrict__ W_hh,
    const float* __restrict__ w1, const float* __restrict__ w2,
    _Float16* __restrict__ Wf, _Float16* __restrict__ w1p,
    _Float16* __restrict__ w2p) {
  int i = blockIdx.x * 256 + threadIdx.x;     // grid covers 116736
  if (i < 192 * 96) {
    int g = i / 96, k = i - g * 96;
    float v = (k < 64) ? W_hh[g * 64 + k] : ((k < 70) ? W_ih[g * 6 + (k - 64)] : 0.f);
    Wf[i] = (_Float16)v;
  }
  int j = i - 192 * 96;
  if (j >= 0 && j < 32768) {
    int kt = j >> 11, ntl = (j >> 10) & 1, kf = (j >> 9) & 1;
    int lane = (j >> 3) & 63, e = j & 7;
    int q = lane >> 4, c = lane & 15;
    int row = kt * 32 + ntl * 16 + c;
    int h = kf * 32 + q * 8 + e;
    w1p[j] = (_Float16)w1[row * 64 + h];
  }
  int l = j - 32768;
  if (l >= 0 && l < 65536) {
    int kt = l >> 12, nt = (l >> 9) & 7;
    int lane = (l >> 3) & 63, e = l & 7;
    int q = lane >> 4, c = lane & 15;
    int row = nt * 16 + c;
    int k = kt * 32 + q * 8 + e;
    w2p[l] = (_Float16)w2[row * 512 + k];
  }
}

// ---------------------------------------------------------------- fused (wave-specialized)
// Block = 8 waves / 512 thr, grid 200, 2 waves/SIMD. Waves 0-3: GRU producer
// (exact R11 step: 16 rows, gate-split, double-buffered 16-step hist, one
// lgkm-only barrier per step). Waves 4-7: MLP consumer for the PREVIOUS
// chunk — per barrier interval 2 k-chunks of layer1+layer2-half (F2 split in
// 2 passes so acc2 = 64 regs). m114: co-resident waves co-schedule MFMA+VALU,
// so the MLP rides the GRU's idle pipes instead of its serial path (the R10/
// R12 additive failure). sx never materializes; last chunk drained by all 8.
__global__ __launch_bounds__(512, 2) void fused_kernel(
    const float* __restrict__ x, const _Float16* __restrict__ Wf,
    const float* __restrict__ b_ih, const float* __restrict__ b_hh,
    const _Float16* __restrict__ w1p, const _Float16* __restrict__ w2p,
    const float* __restrict__ b1, const float* __restrict__ b2,
    const float* __restrict__ w3, const float* __restrict__ b3,
    float* __restrict__ out) {
  __shared__ __align__(16) _Float16 hist[2][16][16][72];  // 72 KB
  __shared__ __align__(16) _Float16 xs[Tdim][16][8];      // 32 KB
  __shared__ __align__(16) _Float16 rep[8][4][512];       // 32 KB
  const int tid = threadIdx.x;
  const int lane = tid & 63;
  const int w = tid >> 6;                     // wave id 0..7
  const int c = lane & 15;
  const int q = lane >> 4;
  const bool gruw = (w < 4);
  const int wv = w - 4;                       // MLP wave id 0..3
  const float b3v = b3[0];
  const int nbase = blockIdx.x * 16;

  // ---- preload x for this block's 16 rows, pre-converted to fp16
  for (int i = 0; i < 4; i++) {
    int idx = i * 512 + tid;                  // 0..2047 = (t, row)
    int t = idx >> 4, row = idx & 15;
    int nr = nbase + row;                     // n = z*32 + b
    const float* p = x + (size_t)(nr & 31) * (Tdim * Zdim * Sdim)
                       + (size_t)t * (Zdim * Sdim) + (size_t)(nr >> 5) * Sdim;
    f16x8 v;
    v[0] = (_Float16)p[0]; v[1] = (_Float16)p[1]; v[2] = (_Float16)p[2];
    v[3] = (_Float16)p[3]; v[4] = (_Float16)p[4]; v[5] = (_Float16)p[5];
    v[6] = (_Float16)0.f;  v[7] = (_Float16)0.f;
    *(f16x8*)&xs[t][row][0] = v;
  }

  // ---- GRU constants (loaded by GRU waves; harmless for MLP waves)
  const int gw = w & 3;
  const int gr0 = gw * 16, gz0 = 64 + gw * 16, gn0 = 128 + gw * 16;
  f16x8 Ar[3], Az[3], Anh[2], Ani;
#pragma unroll
  for (int kf = 0; kf < 3; kf++) {
    Ar[kf] = *(const f16x8*)(Wf + (size_t)(gr0 + c) * 96 + kf * 32 + q * 8);
    Az[kf] = *(const f16x8*)(Wf + (size_t)(gz0 + c) * 96 + kf * 32 + q * 8);
  }
  Anh[0] = *(const f16x8*)(Wf + (size_t)(gn0 + c) * 96 + q * 8);
  Anh[1] = *(const f16x8*)(Wf + (size_t)(gn0 + c) * 96 + 32 + q * 8);
  Ani    = *(const f16x8*)(Wf + (size_t)(gn0 + c) * 96 + 64 + q * 8);
  f32x4 Cr, Cz, Cnh, Cni;
  {
    f32x4 bir = *(const f32x4*)(b_ih + gr0 + q * 4);
    f32x4 bhr = *(const f32x4*)(b_hh + gr0 + q * 4);
    f32x4 biz = *(const f32x4*)(b_ih + gz0 + q * 4);
    f32x4 bhz = *(const f32x4*)(b_hh + gz0 + q * 4);
#pragma unroll
    for (int r = 0; r < 4; r++) { Cr[r] = bir[r] + bhr[r]; Cz[r] = biz[r] + bhz[r]; }
    Cnh = *(const f32x4*)(b_hh + gn0 + q * 4);
    Cni = *(const f32x4*)(b_ih + gn0 + q * 4);
  }

  __syncthreads();                            // xs ready

  f16x8 Bh0 = {0, 0, 0, 0, 0, 0, 0, 0};
  f16x8 Bh1 = {0, 0, 0, 0, 0, 0, 0, 0};
  f32x4 hprev = {0.f, 0.f, 0.f, 0.f};
  const f32x4 zero4 = {0.f, 0.f, 0.f, 0.f};

  // GRU pipeline seeds for t=0
  f32x4 Dr_s = Cr, Dz_s = Cz, Dni_s = Cni;
  if (gruw) {
    f16x8 xv8 = *(const f16x8*)&xs[0][c][0];
    f16x8 Bx;
#pragma unroll
    for (int j = 0; j < 8; j++) Bx[j] = (q == 0) ? xv8[j] : (_Float16)0.f;
    Dni_s = __builtin_amdgcn_mfma_f32_16x16x32_f16(Ani, Bx, Cni, 0, 0, 0);
    Dr_s  = __builtin_amdgcn_mfma_f32_16x16x32_f16(Ar[2], Bx, Cr, 0, 0, 0);
    Dz_s  = __builtin_amdgcn_mfma_f32_16x16x32_f16(Az[2], Bx, Cz, 0, 0, 0);
  }

  // MLP persistent state (64 + 4 regs)
  f32x4 acc2[4][4];
  float part[4];

#pragma unroll 1
  for (int tch = 0; tch < 8; tch++) {
    const int buf = tch & 1;
    const int pbuf = buf ^ 1;
    if (!gruw) {
#pragma unroll
      for (int gi = 0; gi < 4; gi++) {
        part[gi] = 0.f;
#pragma unroll
        for (int nt = 0; nt < 4; nt++) acc2[gi][nt] = zero4;
      }
    }
#pragma unroll 1
    for (int tc = 0; tc < 16; tc++) {
      if (gruw) {
        // ---------------- GRU step t = tch*16+tc (R11-exact)
        const int t = tch * 16 + tc;
        f32x4 Dnh0 = __builtin_amdgcn_mfma_f32_16x16x32_f16(Anh[0], Bh0, Cnh, 0, 0, 0);
        f32x4 Dr0  = __builtin_amdgcn_mfma_f32_16x16x32_f16(Ar[0], Bh0, Dr_s, 0, 0, 0);
        f32x4 Dz0  = __builtin_amdgcn_mfma_f32_16x16x32_f16(Az[0], Bh0, Dz_s, 0, 0, 0);
        f32x4 Dnh1 = __builtin_amdgcn_mfma_f32_16x16x32_f16(Anh[1], Bh1, zero4, 0, 0, 0);
        f32x4 Dr1  = __builtin_amdgcn_mfma_f32_16x16x32_f16(Ar[1], Bh1, zero4, 0, 0, 0);
        f32x4 Dz1  = __builtin_amdgcn_mfma_f32_16x16x32_f16(Az[1], Bh1, zero4, 0, 0, 0);
        f16x4 pk;
#pragma unroll
        for (int r = 0; r < 4; r++) {
          float rr = sigmoidf_fast(Dr0[r] + Dr1[r]);
          float zg = sigmoidf_fast(Dz0[r] + Dz1[r]);
          float nn = tanhf_fast(Dni_s[r] + rr * (Dnh0[r] + Dnh1[r]));
          float hnew = nn + zg * (hprev[r] - nn);
          hprev[r] = hnew;
          pk[r] = (_Float16)hnew;
        }
        *(f16x4*)&hist[buf][tc][c][gw * 16 + q * 4] = pk;
        if (t + 1 < Tdim) {
          f16x8 xv8 = *(const f16x8*)&xs[t + 1][c][0];
          f16x8 Bx;
#pragma unroll
          for (int j = 0; j < 8; j++) Bx[j] = (q == 0) ? xv8[j] : (_Float16)0.f;
          Dni_s = __builtin_amdgcn_mfma_f32_16x16x32_f16(Ani, Bx, Cni, 0, 0, 0);
          Dr_s  = __builtin_amdgcn_mfma_f32_16x16x32_f16(Ar[2], Bx, Cr, 0, 0, 0);
          Dz_s  = __builtin_amdgcn_mfma_f32_16x16x32_f16(Az[2], Bx, Cz, 0, 0, 0);
        }
      } else if (tch > 0) {
        // ---------------- MLP: prev chunk, 4 groups; pass = F2 half; 2 kt
        const int pass = tc >> 3;
        const int k0 = (tc & 7) * 2;
        f16x8 Bs0[4], Bs1[4];
#pragma unroll
        for (int gi = 0; gi < 4; gi++) {
          Bs0[gi] = *(const f16x8*)&hist[pbuf][wv * 4 + gi][c][q * 8];
          Bs1[gi] = *(const f16x8*)&hist[pbuf][wv * 4 + gi][c][32 + q * 8];
        }
#pragma unroll
        for (int kk = 0; kk < 2; kk++) {
          const int kt = k0 + kk;
          const _Float16* w1g = w1p + (size_t)kt * 2048 + lane * 8;
          const _Float16* w2g = w2p + (size_t)kt * 4096 + pass * 2048 + lane * 8;
          f16x8 W1v[4], W2v[4];
#pragma unroll
          for (int f = 0; f < 4; f++) W1v[f] = *(const f16x8*)(w1g + f * 512);
#pragma unroll
          for (int nt = 0; nt < 4; nt++) W2v[nt] = *(const f16x8*)(w2g + nt * 512);
          f32x4 bb1a = *(const f32x4*)(b1 + kt * 32 + q * 4);
          f32x4 bb1b = *(const f32x4*)(b1 + kt * 32 + 16 + q * 4);
#pragma unroll
          for (int ntl = 0; ntl < 2; ntl++) {
            const int roff = ((2 * ntl + (q >> 1)) * 16 + c) * 8 + (q & 1) * 4;
#pragma unroll
            for (int gi = 0; gi < 4; gi++) {
              f32x4 cc = __builtin_amdgcn_mfma_f32_16x16x32_f16(W1v[ntl * 2], Bs0[gi], ntl ? bb1b : bb1a, 0, 0, 0);
              cc = __builtin_amdgcn_mfma_f32_16x16x32_f16(W1v[ntl * 2 + 1], Bs1[gi], cc, 0, 0, 0);
              f16x4 pk2;
#pragma unroll
              for (int r = 0; r < 4; r++)
                pk2[r] = (_Float16)(cc[r] > 0.f ? cc[r] : 0.f);
              *(f16x4*)&rep[w][gi][roff] = pk2;
            }
          }
          f16x8 Ba[4];
#pragma unroll
          for (int gi = 0; gi < 4; gi++)
            Ba[gi] = *(const f16x8*)&rep[w][gi][lane * 8];
#pragma unroll
          for (int nt = 0; nt < 4; nt++)
#pragma unroll
            for (int gi = 0; gi < 4; gi++)
              acc2[gi][nt] = __builtin_amdgcn_mfma_f32_16x16x32_f16(W2v[nt], Ba[gi], acc2[gi][nt], 0, 0, 0);
        }
        if ((tc & 7) == 7) {                  // end of pass: fold layer3 half
#pragma unroll
          for (int nt = 0; nt < 4; nt++) {
            f32x4 bb = *(const f32x4*)(b2 + pass * 64 + nt * 16 + q * 4);
            f32x4 ww = *(const f32x4*)(w3 + pass * 64 + nt * 16 + q * 4);
#pragma unroll
            for (int gi = 0; gi < 4; gi++) {
#pragma unroll
              for (int r = 0; r < 4; r++) {
                float v = acc2[gi][nt][r] + bb[r];
                v = v > 0.f ? v : 0.f;
                part[gi] = fmaf(v, ww[r], part[gi]);
              }
              acc2[gi][nt] = zero4;
            }
          }
          if (pass == 1) {                    // chunk done: reduce + store
#pragma unroll
            for (int gi = 0; gi < 4; gi++) {
              part[gi] += __shfl_xor(part[gi], 16, 64);
              part[gi] += __shfl_xor(part[gi], 32, 64);
              if (q == 0)
                out[(size_t)(nbase + c) * Tdim + (tch - 1) * 16 + wv * 4 + gi] = part[gi] + b3v;
            }
          }
        }
      }
      __syncthreads();                        // common per-step barrier
      if (gruw) {
        Bh0 = *(const f16x8*)&hist[buf][tc][c][q * 8];
        Bh1 = *(const f16x8*)&hist[buf][tc][c][32 + q * 8];
      }
    } // tc
  } // tch

  // ---- drain: chunk 7 (hist[1]) by ALL 8 waves, 2 groups (32 rows) each
  {
    f16x8 Bs0[2], Bs1[2];
    f32x4 acc[2][8];
#pragma unroll
    for (int gi = 0; gi < 2; gi++) {
      Bs0[gi] = *(const f16x8*)&hist[1][w * 2 + gi][c][q * 8];
      Bs1[gi] = *(const f16x8*)&hist[1][w * 2 + gi][c][32 + q * 8];
#pragma unroll
      for (int nt = 0; nt < 8; nt++) acc[gi][nt] = zero4;
    }
#pragma unroll 1
    for (int kt = 0; kt < 16; kt++) {
      const _Float16* w1g = w1p + (size_t)kt * 2048 + lane * 8;
      const _Float16* w2g = w2p + (size_t)kt * 4096 + lane * 8;
      f16x8 W1v[4], W2v[8];
#pragma unroll
      for (int f = 0; f < 4; f++) W1v[f] = *(const f16x8*)(w1g + f * 512);
#pragma unroll
      for (int nt = 0; nt < 8; nt++) W2v[nt] = *(const f16x8*)(w2g + nt * 512);
      f32x4 bb1a = *(const f32x4*)(b1 + kt * 32 + q * 4);
      f32x4 bb1b = *(const f32x4*)(b1 + kt * 32 + 16 + q * 4);
#pragma unroll
      for (int ntl = 0; ntl < 2; ntl++) {
        const int roff = ((2 * ntl + (q >> 1)) * 16 + c) * 8 + (q & 1) * 4;
#pragma unroll
        for (int gi = 0; gi < 2; gi++) {
          f32x4 cc = __builtin_amdgcn_mfma_f32_16x16x32_f16(W1v[ntl * 2], Bs0[gi], ntl ? bb1b : bb1a, 0, 0, 0);
          cc = __builtin_amdgcn_mfma_f32_16x16x32_f16(W1v[ntl * 2 + 1], Bs1[gi], cc, 0, 0, 0);
          f16x4 pk2;
#pragma unroll
          for (int r = 0; r < 4; r++)
            pk2[r] = (_Float16)(cc[r] > 0.f ? cc[r] : 0.f);
          *(f16x4*)&rep[w][gi][roff] = pk2;
        }
      }
      f16x8 Ba[2];
#pragma unroll
      for (int gi = 0; gi < 2; gi++)
        Ba[gi] = *(const f16x8*)&rep[w][gi][lane * 8];
#pragma unroll
      for (int nt = 0; nt < 8; nt++)
#pragma unroll
        for (int gi = 0; gi < 2; gi++)
          acc[gi][nt] = __builtin_amdgcn_mfma_f32_16x16x32_f16(W2v[nt], Ba[gi], acc[gi][nt], 0, 0, 0);
    }
#pragma unroll
    for (int gi = 0; gi < 2; gi++) {
      float pt = 0.f;
#pragma unroll
      for (int nt = 0; nt < 8; nt++) {
        f32x4 bb = *(const f32x4*)(b2 + nt * 16 + q * 4);
        f32x4 ww = *(const f32x4*)(w3 + nt * 16 + q * 4);
#pragma unroll
        for (int r = 0; r < 4; r++) {
          float v = acc[gi][nt][r] + bb[r];
          v = v > 0.f ? v : 0.f;
          pt = fmaf(v, ww[r], pt);
        }
      }
      pt += __shfl_xor(pt, 16, 64);
      pt += __shfl_xor(pt, 32, 64);
      if (q == 0)
        out[(size_t)(nbase + c) * Tdim + 112 + w * 2 + gi] = pt + b3v;
    }
  }
}

// ----------------------------------------------------------------
extern "C" void kernel_launch(void* const* d_in, const int* in_sizes, int n_in,
                              void* d_out, int out_size, void* d_ws, size_t ws_size,
                              hipStream_t stream) {
  const float* x    = (const float*)d_in[0];
  const float* W_ih = (const float*)d_in[1];
  const float* W_hh = (const float*)d_in[2];
  const float* b_ih = (const float*)d_in[3];
  const float* b_hh = (const float*)d_in[4];
  const float* w1   = (const float*)d_in[5];
  const float* b1   = (const float*)d_in[6];
  const float* w2   = (const float*)d_in[7];
  const float* b2   = (const float*)d_in[8];
  const float* w3   = (const float*)d_in[9];
  const float* b3   = (const float*)d_in[10];
  float* out = (float*)d_out;

  char* ws = (char*)d_ws;
  _Float16* Wf  = (_Float16*)ws;                          // 36,864 B
  _Float16* w1p = (_Float16*)(ws + 36864);                // 65,536 B
  _Float16* w2p = (_Float16*)(ws + 36864 + 65536);        // 131,072 B

  hipLaunchKernelGGL(prep_kernel, dim3(456), dim3(256), 0, stream,
                     W_ih, W_hh, w1, w2, Wf, w1p, w2p);
  hipLaunchKernelGGL(fused_kernel, dim3(ZB / 16), dim3(512), 0, stream,
                     x, Wf, b_ih, b_hh, w1p, w2p, b1, b2, w3, b3, out);
}